// Round 1
// baseline (245.718 us; speedup 1.0000x reference)
//
#include <hip/hip_runtime.h>
#include <math.h>

#define B 8
#define N 2048
#define FIN 128
#define FOUT 64
#define NS 0.2f

// ---------------------------------------------------------------------------
// K1: per row (b,n): h = x@W (64 outputs), s1 = h.a1, s2 = h.a2,
//     u = e^{s1}, uq = e^{0.2 s1}, e2 = e^{s2}, eq2 = e^{0.2 s2}
// block = 256 threads = 4 rows x 64 lanes (one wave per row)
// ---------------------------------------------------------------------------
__global__ void k_hs(const float* __restrict__ x, const float* __restrict__ W,
                     const float* __restrict__ a, float* __restrict__ h,
                     float* __restrict__ s1, float* __restrict__ s2,
                     float* __restrict__ u, float* __restrict__ uq,
                     float* __restrict__ e2, float* __restrict__ eq2) {
  __shared__ float xs[4][FIN];
  const int row0 = blockIdx.x * 4;
  const int lane = threadIdx.x & 63;
  const int r = threadIdx.x >> 6;

  for (int t = threadIdx.x; t < 4 * FIN; t += 256) {
    int rr = t >> 7, kk = t & 127;
    xs[rr][kk] = x[(size_t)(row0 + rr) * FIN + kk];
  }
  __syncthreads();

  float acc = 0.f;
#pragma unroll 8
  for (int k = 0; k < FIN; ++k)
    acc = fmaf(xs[r][k], W[k * FOUT + lane], acc);

  const int row = row0 + r;
  h[(size_t)row * FOUT + lane] = acc;

  float v1 = acc * a[lane];
  float v2 = acc * a[FOUT + lane];
#pragma unroll
  for (int off = 32; off > 0; off >>= 1) {
    v1 += __shfl_xor(v1, off, 64);
    v2 += __shfl_xor(v2, off, 64);
  }
  if (lane == 0) {
    s1[row] = v1;
    s2[row] = v2;
    u[row] = expf(v1);
    uq[row] = expf(NS * v1);
    e2[row] = expf(v2);
    eq2[row] = expf(NS * v2);
  }
}

// ---------------------------------------------------------------------------
// K2: per (b,j): Z_j = e2_j * sum_{i: s1_i+s2_j>=0} u_i
//                     + eq2_j * sum_{i: s1_i+s2_j<0} uq_i
//     A_j = e2_j / Z_j,  Bc_j = eq2_j / Z_j
// cond(i,j) <=> u_i * e2_j >= 1  (monotone equivalent; boundary continuous)
// block = 256 threads = 64 j x 4 i-chunks of 512; grid = B * (N/64)
// ---------------------------------------------------------------------------
__global__ void k_z(const float* __restrict__ u, const float* __restrict__ uq,
                    const float* __restrict__ e2, const float* __restrict__ eq2,
                    float* __restrict__ A, float* __restrict__ Bc) {
  __shared__ float us[N], uqs[N];
  __shared__ float rsu[4][64], rsq[4][64];
  const int b = blockIdx.x / (N / 64);
  const int j0 = (blockIdx.x % (N / 64)) * 64;
  const int jl = threadIdx.x & 63;
  const int ic = threadIdx.x >> 6;

  for (int t = threadIdx.x; t < N; t += 256) {
    us[t] = u[b * N + t];
    uqs[t] = uq[b * N + t];
  }
  __syncthreads();

  const float E = e2[b * N + j0 + jl];
  float su = 0.f, sq = 0.f;
  const int ibeg = ic * (N / 4), iend = ibeg + (N / 4);
#pragma unroll 4
  for (int i = ibeg; i < iend; ++i) {
    float ui = us[i];
    bool cond = (ui * E >= 1.0f);
    su += cond ? ui : 0.f;
    sq += cond ? 0.f : uqs[i];
  }
  rsu[ic][jl] = su;
  rsq[ic][jl] = sq;
  __syncthreads();

  if (threadIdx.x < 64) {
    int j = j0 + threadIdx.x;
    float SU = rsu[0][threadIdx.x] + rsu[1][threadIdx.x] +
               rsu[2][threadIdx.x] + rsu[3][threadIdx.x];
    float SQ = rsq[0][threadIdx.x] + rsq[1][threadIdx.x] +
               rsq[2][threadIdx.x] + rsq[3][threadIdx.x];
    float Ej = e2[b * N + j];
    float Eq = eq2[b * N + j];
    float Z = Ej * SU + Eq * SQ;
    A[b * N + j] = Ej / Z;
    Bc[b * N + j] = Eq / Z;
  }
}

// ---------------------------------------------------------------------------
// K3: h'_{b,i,f} = sum_j (cond ? u_i*A_j : uq_i*Bc_j) * h_{b,j,f}
//     out = lrelu(h')
// block = 256 threads = 32 i x 8 f-groups (8 f each); j staged in LDS by 128
// grid = B * (N/32)
// ---------------------------------------------------------------------------
#define IT 32
#define JT 128
__global__ void k_hp(const float* __restrict__ h, const float* __restrict__ s1,
                     const float* __restrict__ u, const float* __restrict__ uq,
                     const float* __restrict__ s2, const float* __restrict__ A,
                     const float* __restrict__ Bc, float* __restrict__ out) {
  __shared__ float hc[JT * FOUT];       // 32 KB
  __shared__ float Ach[JT], Bch[JT], s2ch[JT];
  const int b = blockIdx.x / (N / IT);
  const int i0 = (blockIdx.x % (N / IT)) * IT;
  const int il = threadIdx.x >> 3;      // 0..31
  const int fg = threadIdx.x & 7;       // f0 = fg*8
  const int i = i0 + il;

  const float my_s1 = s1[b * N + i];
  const float my_u = u[b * N + i];
  const float my_uq = uq[b * N + i];

  float acc0 = 0.f, acc1 = 0.f, acc2 = 0.f, acc3 = 0.f;
  float acc4 = 0.f, acc5 = 0.f, acc6 = 0.f, acc7 = 0.f;

  for (int j0 = 0; j0 < N; j0 += JT) {
    // stage h chunk (contiguous) as float4
    const float4* src = (const float4*)(h + ((size_t)b * N + j0) * FOUT);
    float4* dst = (float4*)hc;
    for (int t = threadIdx.x; t < JT * FOUT / 4; t += 256)
      dst[t] = src[t];
    for (int t = threadIdx.x; t < JT; t += 256) {
      Ach[t] = A[b * N + j0 + t];
      Bch[t] = Bc[b * N + j0 + t];
      s2ch[t] = s2[b * N + j0 + t];
    }
    __syncthreads();

#pragma unroll 4
    for (int jj = 0; jj < JT; ++jj) {
      bool cond = (my_s1 + s2ch[jj]) >= 0.f;
      float coef = cond ? my_u * Ach[jj] : my_uq * Bch[jj];
      const float* hr = &hc[jj * FOUT + fg * 8];
      float4 h0 = *(const float4*)hr;
      float4 h1 = *(const float4*)(hr + 4);
      acc0 = fmaf(coef, h0.x, acc0);
      acc1 = fmaf(coef, h0.y, acc1);
      acc2 = fmaf(coef, h0.z, acc2);
      acc3 = fmaf(coef, h0.w, acc3);
      acc4 = fmaf(coef, h1.x, acc4);
      acc5 = fmaf(coef, h1.y, acc5);
      acc6 = fmaf(coef, h1.z, acc6);
      acc7 = fmaf(coef, h1.w, acc7);
    }
    __syncthreads();
  }

  float* op = out + ((size_t)b * N + i) * FOUT + fg * 8;
  float v;
  v = acc0; op[0] = v >= 0.f ? v : NS * v;
  v = acc1; op[1] = v >= 0.f ? v : NS * v;
  v = acc2; op[2] = v >= 0.f ? v : NS * v;
  v = acc3; op[3] = v >= 0.f ? v : NS * v;
  v = acc4; op[4] = v >= 0.f ? v : NS * v;
  v = acc5; op[5] = v >= 0.f ? v : NS * v;
  v = acc6; op[6] = v >= 0.f ? v : NS * v;
  v = acc7; op[7] = v >= 0.f ? v : NS * v;
}

extern "C" void kernel_launch(void* const* d_in, const int* in_sizes, int n_in,
                              void* d_out, int out_size, void* d_ws, size_t ws_size,
                              hipStream_t stream) {
  const float* x = (const float*)d_in[0];   // (8,2048,128)
  const float* W = (const float*)d_in[1];   // (128,64)
  const float* a = (const float*)d_in[2];   // (128,1)
  float* out = (float*)d_out;               // (8,2048,64)

  float* ws = (float*)d_ws;
  float* h = ws;                         // B*N*FOUT = 1,048,576 floats
  float* s1 = h + (size_t)B * N * FOUT;  // B*N each below
  float* s2 = s1 + B * N;
  float* u = s2 + B * N;
  float* uq = u + B * N;
  float* e2 = uq + B * N;
  float* eq2 = e2 + B * N;
  float* A = eq2 + B * N;
  float* Bc = A + B * N;

  k_hs<<<B * N / 4, 256, 0, stream>>>(x, W, a, h, s1, s2, u, uq, e2, eq2);
  k_z<<<B * (N / 64), 256, 0, stream>>>(u, uq, e2, eq2, A, Bc);
  k_hp<<<B * (N / IT), 256, 0, stream>>>(h, s1, u, uq, s2, A, Bc, out);
}

// Round 2
// 90.549 us; speedup vs baseline: 2.7136x; 2.7136x over previous
//
#include <hip/hip_runtime.h>
#include <math.h>

#define B 8
#define N 2048
#define NP1 2049
#define FIN 128
#define FOUT 64
#define NS 0.2f

typedef unsigned long long u64;

__device__ __forceinline__ unsigned f2u(float f) {
  unsigned u = __float_as_uint(f);
  return (u & 0x80000000u) ? ~u : (u | 0x80000000u);
}
__device__ __forceinline__ float u2f(unsigned v) {
  unsigned u = (v & 0x80000000u) ? (v ^ 0x80000000u) : ~v;
  return __uint_as_float(u);
}

// ---------------------------------------------------------------------------
// K1: per row: h = x@W, s1 = h.a1, s2 = h.a2, u/uq/e2/eq2 = exps
// block = 256 = 4 rows x 64 lanes
// ---------------------------------------------------------------------------
__global__ void k_hs(const float* __restrict__ x, const float* __restrict__ W,
                     const float* __restrict__ a, float* __restrict__ h,
                     float* __restrict__ s1, float* __restrict__ s2,
                     float* __restrict__ u, float* __restrict__ uq,
                     float* __restrict__ e2, float* __restrict__ eq2) {
  __shared__ float xs[4][FIN];
  const int row0 = blockIdx.x * 4;
  const int lane = threadIdx.x & 63;
  const int r = threadIdx.x >> 6;

  for (int t = threadIdx.x; t < 4 * FIN; t += 256) {
    int rr = t >> 7, kk = t & 127;
    xs[rr][kk] = x[(size_t)(row0 + rr) * FIN + kk];
  }
  __syncthreads();

  float acc = 0.f;
#pragma unroll 8
  for (int k = 0; k < FIN; ++k)
    acc = fmaf(xs[r][k], W[k * FOUT + lane], acc);

  const int row = row0 + r;
  h[(size_t)row * FOUT + lane] = acc;

  float v1 = acc * a[lane];
  float v2 = acc * a[FOUT + lane];
#pragma unroll
  for (int off = 32; off > 0; off >>= 1) {
    v1 += __shfl_xor(v1, off, 64);
    v2 += __shfl_xor(v2, off, 64);
  }
  if (lane == 0) {
    s1[row] = v1;
    s2[row] = v2;
    u[row] = expf(v1);
    uq[row] = expf(NS * v1);
    e2[row] = expf(v2);
    eq2[row] = expf(NS * v2);
  }
}

// ---------------------------------------------------------------------------
// K2: per (batch, key-type): bitonic sort 2048 (key|idx) u64 in LDS.
// type 0: key = s1 -> write s1s, then gather u,uq in sorted order and
//         Hillis-Steele scan -> Pu[0..N], Pq[0..N]
// type 1: key = s2 -> write s2s, idx2
// grid = 2*B blocks of 1024 threads
// ---------------------------------------------------------------------------
__global__ __launch_bounds__(1024) void k_sort(
    const float* __restrict__ s1, const float* __restrict__ s2,
    const float* __restrict__ u, const float* __restrict__ uq,
    float* __restrict__ s1s, float* __restrict__ Pu, float* __restrict__ Pq,
    float* __restrict__ s2s, int* __restrict__ idx2) {
  __shared__ u64 keys[N];
  __shared__ float sU[N], sQ[N];
  const int type = blockIdx.x & 1;
  const int b = blockIdx.x >> 1;
  const int tid = threadIdx.x;
  const float* ksrc = type ? s2 : s1;

  for (int t = tid; t < N; t += 1024)
    keys[t] = ((u64)f2u(ksrc[b * N + t]) << 32) | (unsigned)t;
  __syncthreads();

  for (int k = 2; k <= N; k <<= 1) {
    for (int j = k >> 1; j > 0; j >>= 1) {
      for (int t = tid; t < N; t += 1024) {
        int p = t ^ j;
        if (p > t) {
          u64 av = keys[t], cv = keys[p];
          bool asc = ((t & k) == 0);
          if ((av > cv) == asc) { keys[t] = cv; keys[p] = av; }
        }
      }
      __syncthreads();
    }
  }

  if (type == 1) {
    for (int t = tid; t < N; t += 1024) {
      u64 kv = keys[t];
      s2s[b * N + t] = u2f((unsigned)(kv >> 32));
      idx2[b * N + t] = (int)(kv & 0xffffffffu);
    }
  } else {
    for (int t = tid; t < N; t += 1024) {
      u64 kv = keys[t];
      s1s[b * N + t] = u2f((unsigned)(kv >> 32));
      int idx = (int)(kv & 0xffffffffu);
      sU[t] = u[b * N + idx];
      sQ[t] = uq[b * N + idx];
    }
    __syncthreads();
    for (int off = 1; off < N; off <<= 1) {
      const int t0 = tid, t1 = tid + 1024;
      float nU0 = sU[t0] + (t0 >= off ? sU[t0 - off] : 0.f);
      float nQ0 = sQ[t0] + (t0 >= off ? sQ[t0 - off] : 0.f);
      float nU1 = sU[t1] + sU[t1 - off];
      float nQ1 = sQ[t1] + sQ[t1 - off];
      __syncthreads();
      sU[t0] = nU0; sQ[t0] = nQ0;
      sU[t1] = nU1; sQ[t1] = nQ1;
      __syncthreads();
    }
    for (int t = tid; t < N; t += 1024) {
      Pu[b * NP1 + 1 + t] = sU[t];
      Pq[b * NP1 + 1 + t] = sQ[t];
    }
    if (tid == 0) { Pu[b * NP1] = 0.f; Pq[b * NP1] = 0.f; }
  }
}

// ---------------------------------------------------------------------------
// K3: per j: c = lower_bound(s1s, -s2_j); Z from scalar prefix sums;
//     A_j = e2_j/Z, Bc_j = eq2_j/Z.  grid = B*(N/256) x 256
// ---------------------------------------------------------------------------
__global__ void k_z(const float* __restrict__ s1s, const float* __restrict__ Pu,
                    const float* __restrict__ Pq, const float* __restrict__ s2,
                    const float* __restrict__ e2, const float* __restrict__ eq2,
                    float* __restrict__ A, float* __restrict__ Bc) {
  __shared__ float ks[N];
  const int b = blockIdx.x >> 3;
  const int j0 = (blockIdx.x & 7) * 256;
  for (int t = threadIdx.x; t < N; t += 256) ks[t] = s1s[b * N + t];
  __syncthreads();
  const int j = j0 + threadIdx.x;
  const float t = -s2[b * N + j];
  int lo = 0, hi = N;
  while (lo < hi) {
    int mid = (lo + hi) >> 1;
    if (ks[mid] < t) lo = mid + 1; else hi = mid;
  }
  const int c = lo;
  const float SU = Pu[b * NP1 + N] - Pu[b * NP1 + c];
  const float SQ = Pq[b * NP1 + c];
  const float E = e2[b * N + j], Eq = eq2[b * N + j];
  const float Z = E * SU + Eq * SQ;
  A[b * N + j] = E / Z;
  Bc[b * N + j] = Eq / Z;
}

// ---------------------------------------------------------------------------
// K4a: chunk totals of A*h and B*h in s2-sorted order (32-row chunks)
// grid = B*64 blocks of 64 threads (lane = f)
// ---------------------------------------------------------------------------
#define NCH 64
#define CHS 32
__global__ void k_scan1(const float* __restrict__ A, const float* __restrict__ Bc,
                        const float* __restrict__ h, const int* __restrict__ idx2,
                        float* __restrict__ ctA, float* __restrict__ ctB) {
  const int b = blockIdx.x >> 6, w = blockIdx.x & 63;
  const int f = threadIdx.x;
  float ta = 0.f, tb = 0.f;
  for (int rr = 0; rr < CHS; ++rr) {
    const int r = w * CHS + rr;
    const int j = idx2[b * N + r];
    const float hv = h[((size_t)b * N + j) * FOUT + f];
    ta = fmaf(A[b * N + j], hv, ta);
    tb = fmaf(Bc[b * N + j], hv, tb);
  }
  ctA[(b * NCH + w) * FOUT + f] = ta;
  ctB[(b * NCH + w) * FOUT + f] = tb;
}

// ---------------------------------------------------------------------------
// K4b: finalize vector scans: PB[c][f] = prefix of B*h (ranks < c),
//      SA[c][f] = suffix of A*h (ranks >= c).  grid = B*64 x 64
// ---------------------------------------------------------------------------
__global__ void k_scan2(const float* __restrict__ A, const float* __restrict__ Bc,
                        const float* __restrict__ h, const int* __restrict__ idx2,
                        const float* __restrict__ ctA, const float* __restrict__ ctB,
                        float* __restrict__ SA, float* __restrict__ PB) {
  const int b = blockIdx.x >> 6, w = blockIdx.x & 63;
  const int f = threadIdx.x;
  float offA = 0.f, offB = 0.f;
  for (int w2 = 0; w2 < NCH; ++w2) {
    const float ta = ctA[(b * NCH + w2) * FOUT + f];
    const float tb = ctB[(b * NCH + w2) * FOUT + f];
    if (w2 > w) offA += ta;
    if (w2 < w) offB += tb;
  }
  float run = offB;
  for (int rr = 0; rr < CHS; ++rr) {
    const int r = w * CHS + rr;
    const int j = idx2[b * N + r];
    const float hv = h[((size_t)b * N + j) * FOUT + f];
    run = fmaf(Bc[b * N + j], hv, run);
    PB[((size_t)b * NP1 + r + 1) * FOUT + f] = run;
  }
  run = offA;
  for (int rr = CHS - 1; rr >= 0; --rr) {
    const int r = w * CHS + rr;
    const int j = idx2[b * N + r];
    const float hv = h[((size_t)b * N + j) * FOUT + f];
    run = fmaf(A[b * N + j], hv, run);
    SA[((size_t)b * NP1 + r) * FOUT + f] = run;
  }
  if (w == 0) {
    PB[((size_t)b * NP1 + 0) * FOUT + f] = 0.f;
    SA[((size_t)b * NP1 + N) * FOUT + f] = 0.f;
  }
}

// ---------------------------------------------------------------------------
// K5: per row i: wave-ballot lower_bound(s2s, -s1_i) -> c;
//     out[f] = lrelu(u_i*SA[c][f] + uq_i*PB[c][f])
// grid = B*N/4 blocks of 256 (4 waves, one row per wave)
// ---------------------------------------------------------------------------
__global__ void k_out(const float* __restrict__ s1, const float* __restrict__ u,
                      const float* __restrict__ uq, const float* __restrict__ s2s,
                      const float* __restrict__ SA, const float* __restrict__ PB,
                      float* __restrict__ out) {
  const int wv = threadIdx.x >> 6;
  const int lane = threadIdx.x & 63;
  const int row = blockIdx.x * 4 + wv;
  const int b = row >> 11;
  const float t = -s1[row];
  const float* ks = s2s + b * N;

  const float v0 = ks[lane * 32];
  const unsigned long long m = __ballot(v0 < t);
  const int m1 = __popcll(m);
  int c;
  if (m1 == 0) {
    c = 0;
  } else {
    const int base = (m1 - 1) * 32;
    const float v1 = ks[base + (lane & 31)];
    const unsigned long long m2 = __ballot((lane < 32) && (v1 < t));
    c = base + __popcll(m2);
  }
  const float sa = SA[((size_t)b * NP1 + c) * FOUT + lane];
  const float pb = PB[((size_t)b * NP1 + c) * FOUT + lane];
  const float v = u[row] * sa + uq[row] * pb;
  out[(size_t)row * FOUT + lane] = v >= 0.f ? v : NS * v;
}

extern "C" void kernel_launch(void* const* d_in, const int* in_sizes, int n_in,
                              void* d_out, int out_size, void* d_ws, size_t ws_size,
                              hipStream_t stream) {
  const float* x = (const float*)d_in[0];   // (8,2048,128)
  const float* W = (const float*)d_in[1];   // (128,64)
  const float* a = (const float*)d_in[2];   // (128,1)
  float* out = (float*)d_out;               // (8,2048,64)

  // h lives in d_out as scratch; k_out overwrites it last.
  float* h = out;

  float* ws = (float*)d_ws;
  float* s1 = ws;                 // B*N
  float* s2 = s1 + B * N;
  float* u = s2 + B * N;
  float* uq = u + B * N;
  float* e2 = uq + B * N;
  float* eq2 = e2 + B * N;
  float* A = eq2 + B * N;
  float* Bc = A + B * N;
  float* s1s = Bc + B * N;
  float* s2s = s1s + B * N;
  int* idx2 = (int*)(s2s + B * N);
  float* Pu = (float*)(idx2 + B * N);   // B*(N+1)
  float* Pq = Pu + B * NP1;
  float* ctA = Pq + B * NP1;            // B*64*64
  float* ctB = ctA + B * NCH * FOUT;
  float* SA = ctB + B * NCH * FOUT;     // B*(N+1)*64
  float* PB = SA + (size_t)B * NP1 * FOUT;

  k_hs<<<B * N / 4, 256, 0, stream>>>(x, W, a, h, s1, s2, u, uq, e2, eq2);
  k_sort<<<2 * B, 1024, 0, stream>>>(s1, s2, u, uq, s1s, Pu, Pq, s2s, idx2);
  k_z<<<B * (N / 256), 256, 0, stream>>>(s1s, Pu, Pq, s2, e2, eq2, A, Bc);
  k_scan1<<<B * NCH, FOUT, 0, stream>>>(A, Bc, h, idx2, ctA, ctB);
  k_scan2<<<B * NCH, FOUT, 0, stream>>>(A, Bc, h, idx2, ctA, ctB, SA, PB);
  k_out<<<B * N / 4, 256, 0, stream>>>(s1, u, uq, s2s, SA, PB, out);
}